// Round 1
// baseline (597.459 us; speedup 1.0000x reference)
//
#include <hip/hip_runtime.h>
#include <math.h>

// Problem constants
#define B_  2
#define L_  2048
#define S_  2048
#define D_  256
#define H_  8
#define HD_ 32
#define ML_ (B_ * L_)   // 4096 rows for x-side matmuls
#define MS_ (B_ * S_)   // 4096 rows for source-side matmuls

// ---------------------------------------------------------------------------
// GEMM NT: C[M,N] = A[M,K] @ B[N,K]^T  (torch Linear), optional fused ReLU.
// 64x64 tile, BK=16, 256 threads, 4x4 per thread, fp32 VALU.
// ---------------------------------------------------------------------------
template <bool RELU>
__global__ __launch_bounds__(256) void gemm_nt(const float* __restrict__ A,
                                               const float* __restrict__ Bm,
                                               float* __restrict__ C,
                                               int M, int N, int K) {
    const int BM = 64, BN = 64, BK = 16;
    __shared__ float As[BK][BM];
    __shared__ float Bs[BK][BN];
    const int tid = threadIdx.x;
    const int tn = tid % 16, tm = tid / 16;
    const int m0 = blockIdx.x * BM, n0 = blockIdx.y * BN;
    float acc[4][4] = {};

    const int r  = tid / 4;        // 0..63 row of tile being staged
    const int kc = (tid % 4) * 4;  // 0,4,8,12

    for (int k0 = 0; k0 < K; k0 += BK) {
        float4 av = *(const float4*)(&A [(size_t)(m0 + r) * K + k0 + kc]);
        float4 bv = *(const float4*)(&Bm[(size_t)(n0 + r) * K + k0 + kc]);
        As[kc + 0][r] = av.x; As[kc + 1][r] = av.y;
        As[kc + 2][r] = av.z; As[kc + 3][r] = av.w;
        Bs[kc + 0][r] = bv.x; Bs[kc + 1][r] = bv.y;
        Bs[kc + 2][r] = bv.z; Bs[kc + 3][r] = bv.w;
        __syncthreads();
#pragma unroll
        for (int k = 0; k < BK; ++k) {
            float4 a4 = *(const float4*)&As[k][tm * 4];
            float4 b4 = *(const float4*)&Bs[k][tn * 4];
            float a[4] = {a4.x, a4.y, a4.z, a4.w};
            float b[4] = {b4.x, b4.y, b4.z, b4.w};
#pragma unroll
            for (int i = 0; i < 4; ++i)
#pragma unroll
                for (int j = 0; j < 4; ++j) acc[i][j] += a[i] * b[j];
        }
        __syncthreads();
    }
#pragma unroll
    for (int i = 0; i < 4; ++i) {
        const int m = m0 + tm * 4 + i;
#pragma unroll
        for (int j = 0; j < 4; ++j) {
            float v = acc[i][j];
            if (RELU) v = fmaxf(v, 0.f);
            C[(size_t)m * N + n0 + tn * 4 + j] = v;
        }
    }
}

// ---------------------------------------------------------------------------
// Flash-style attention, fp32.
// grid (L/64, H, B), block 256. Each block: one (b,h), 64 q-rows.
// Thread t owns row l=t/4; phase A computes 16 scores (s-block t%4),
// phase C accumulates 8 output dims (d-block t%4).
// score = (q.k)/sqrt(32) * attn_factor[b,l,s]; softmax over S (online).
// ---------------------------------------------------------------------------
__global__ __launch_bounds__(256) void attn_kernel(const float* __restrict__ Q,
                                                   const float* __restrict__ Kp,
                                                   const float* __restrict__ Vp,
                                                   const float* __restrict__ F,
                                                   float* __restrict__ O) {
    const int TL = 64, TS = 64;
    const int b = blockIdx.z, h = blockIdx.y, l0 = blockIdx.x * TL;
    const int tid = threadIdx.x;

    __shared__ float Qs[TL][HD_];
    __shared__ float Ks[TS][HD_];
    __shared__ float Vs[TS][HD_];
    __shared__ float Sc[TL][TS + 1];

    for (int i = tid; i < TL * HD_; i += 256) {
        int rr = i / HD_, c = i % HD_;
        Qs[rr][c] = Q[((size_t)(b * L_ + l0 + rr)) * D_ + h * HD_ + c];
    }

    const int l  = tid / 4;
    const int sb = (tid % 4) * 16;
    const int d0 = (tid % 4) * 8;
    const float scale = 0.17677669529663687f;  // 1/sqrt(32)

    float m_run = -INFINITY, l_run = 0.f;
    float oacc[8] = {};

    for (int s0 = 0; s0 < S_; s0 += TS) {
        __syncthreads();  // previous phase C done before overwriting Ks/Vs/Sc
        for (int i = tid; i < TS * HD_; i += 256) {
            int rr = i / HD_, c = i % HD_;
            size_t src = ((size_t)(b * S_ + s0 + rr)) * D_ + h * HD_ + c;
            Ks[rr][c] = Kp[src];
            Vs[rr][c] = Vp[src];
        }
        __syncthreads();

        // ---- phase A: 16 scores for my row ----
        float sc[16];
        float tmax = -INFINITY;
        const float* frow = &F[((size_t)(b * L_ + l0 + l)) * S_ + s0 + sb];
#pragma unroll
        for (int i = 0; i < 16; ++i) {
            float dot = 0.f;
#pragma unroll
            for (int k = 0; k < HD_; k += 4) {
                float4 q4 = *(const float4*)&Qs[l][k];
                float4 k4 = *(const float4*)&Ks[sb + i][k];
                dot += q4.x * k4.x + q4.y * k4.y + q4.z * k4.z + q4.w * k4.w;
            }
            float v = dot * scale * frow[i];
            sc[i] = v;
            tmax = fmaxf(tmax, v);
        }
        // max across the 4 lanes of this row group (lanes are consecutive)
        tmax = fmaxf(tmax, __shfl_xor(tmax, 1));
        tmax = fmaxf(tmax, __shfl_xor(tmax, 2));
        const float m_new = fmaxf(m_run, tmax);
        const float alpha = expf(m_run - m_new);  // first tile: exp(-inf)=0

        float psum = 0.f;
#pragma unroll
        for (int i = 0; i < 16; ++i) {
            float p = expf(sc[i] - m_new);
            Sc[l][sb + i] = p;
            psum += p;
        }
        psum += __shfl_xor(psum, 1);
        psum += __shfl_xor(psum, 2);
        l_run = l_run * alpha + psum;
        m_run = m_new;
        __syncthreads();

        // ---- phase C: O[l][d0..d0+7] += P[l][:] @ V[:, d0..d0+7] ----
#pragma unroll
        for (int j = 0; j < 8; ++j) oacc[j] *= alpha;
        for (int s = 0; s < TS; ++s) {
            float p = Sc[l][s];
            float4 v0 = *(const float4*)&Vs[s][d0];
            float4 v1 = *(const float4*)&Vs[s][d0 + 4];
            oacc[0] += p * v0.x; oacc[1] += p * v0.y;
            oacc[2] += p * v0.z; oacc[3] += p * v0.w;
            oacc[4] += p * v1.x; oacc[5] += p * v1.y;
            oacc[6] += p * v1.z; oacc[7] += p * v1.w;
        }
    }

    const float inv = 1.f / l_run;
#pragma unroll
    for (int j = 0; j < 8; ++j)
        O[((size_t)(b * L_ + l0 + l)) * D_ + h * HD_ + d0 + j] = oacc[j] * inv;
}

// ---------------------------------------------------------------------------
// LayerNorm over D=256; one block (256 thr) per row. Optional residual add.
// ---------------------------------------------------------------------------
__global__ __launch_bounds__(256) void ln_kernel(const float* __restrict__ X,
                                                 const float* __restrict__ g,
                                                 const float* __restrict__ bb,
                                                 const float* __restrict__ addx,
                                                 float* __restrict__ Y) {
    const int row = blockIdx.x;
    const int tid = threadIdx.x;
    const float x = X[(size_t)row * D_ + tid];
    float s = x, q = x * x;
#pragma unroll
    for (int off = 32; off; off >>= 1) {
        s += __shfl_down(s, off);
        q += __shfl_down(q, off);
    }
    __shared__ float rs[4], rq[4];
    const int wid = tid >> 6, lane = tid & 63;
    if (lane == 0) { rs[wid] = s; rq[wid] = q; }
    __syncthreads();
    const float S = rs[0] + rs[1] + rs[2] + rs[3];
    const float Qs = rq[0] + rq[1] + rq[2] + rq[3];
    const float mean = S * (1.f / D_);
    const float var = Qs * (1.f / D_) - mean * mean;
    float y = (x - mean) * rsqrtf(var + 1e-5f) * g[tid] + bb[tid];
    if (addx) y += addx[(size_t)row * D_ + tid];
    Y[(size_t)row * D_ + tid] = y;
}

// ---------------------------------------------------------------------------
// hcat[row] = [x[row] (256) | m1[row] (256)]
// ---------------------------------------------------------------------------
__global__ __launch_bounds__(256) void concat_kernel(const float* __restrict__ X,
                                                     const float* __restrict__ Mg,
                                                     float* __restrict__ Hc) {
    const int idx = blockIdx.x * 256 + threadIdx.x;  // over 4096*512
    const int row = idx >> 9;
    const int c = idx & 511;
    Hc[idx] = (c < 256) ? X[(size_t)row * 256 + c] : Mg[(size_t)row * 256 + c - 256];
}

// ---------------------------------------------------------------------------
extern "C" void kernel_launch(void* const* d_in, const int* in_sizes, int n_in,
                              void* d_out, int out_size, void* d_ws, size_t ws_size,
                              hipStream_t stream) {
    (void)in_sizes; (void)n_in; (void)out_size; (void)ws_size;
    const float* x   = (const float*)d_in[0];
    const float* src = (const float*)d_in[1];
    const float* F   = (const float*)d_in[2];
    const float* Wq  = (const float*)d_in[3];
    const float* Wk  = (const float*)d_in[4];
    const float* Wv  = (const float*)d_in[5];
    const float* Wm  = (const float*)d_in[6];
    const float* W1  = (const float*)d_in[7];
    const float* W2  = (const float*)d_in[8];
    const float* g1  = (const float*)d_in[9];
    const float* b1  = (const float*)d_in[10];
    const float* g2  = (const float*)d_in[11];
    const float* b2  = (const float*)d_in[12];
    float* out = (float*)d_out;

    // Workspace layout (floats), 6M floats = 24 MB, aliased:
    //   [0,1M)  qw  -> msg (after attn) -> msg2 (after MLP)
    //   [1M,2M) kw  -> m1
    //   [2M,4M) vw,o -> hcat (vw/o dead after attn/Wm-GEMM)
    //   [4M,6M) hbuf
    float* ws   = (float*)d_ws;
    const size_t MF = 1048576;  // 1M floats
    float* qw   = ws;
    float* kw   = ws + 1 * MF;
    float* vw   = ws + 2 * MF;
    float* o    = ws + 3 * MF;
    float* msg  = ws;            // aliases qw (dead)
    float* m1   = ws + 1 * MF;   // aliases kw (dead)
    float* hcat = ws + 2 * MF;   // aliases vw+o (dead), 2M floats
    float* hbuf = ws + 4 * MF;   // 2M floats
    float* msg2 = ws;            // aliases msg (dead)

    dim3 blk(256);
    // Projections
    gemm_nt<false><<<dim3(ML_ / 64, D_ / 64), blk, 0, stream>>>(x,   Wq, qw, ML_, D_, D_);
    gemm_nt<false><<<dim3(MS_ / 64, D_ / 64), blk, 0, stream>>>(src, Wk, kw, MS_, D_, D_);
    gemm_nt<false><<<dim3(MS_ / 64, D_ / 64), blk, 0, stream>>>(src, Wv, vw, MS_, D_, D_);
    // Attention
    attn_kernel<<<dim3(L_ / 64, H_, B_), blk, 0, stream>>>(qw, kw, vw, F, o);
    // Out-proj + LN1
    gemm_nt<false><<<dim3(ML_ / 64, D_ / 64), blk, 0, stream>>>(o, Wm, msg, ML_, D_, D_);
    ln_kernel<<<dim3(ML_), blk, 0, stream>>>(msg, g1, b1, nullptr, m1);
    // MLP
    concat_kernel<<<dim3(ML_ * 512 / 256), blk, 0, stream>>>(x, m1, hcat);
    gemm_nt<true ><<<dim3(ML_ / 64, 512 / 64), blk, 0, stream>>>(hcat, W1, hbuf, ML_, 512, 512);
    gemm_nt<false><<<dim3(ML_ / 64, D_ / 64), blk, 0, stream>>>(hbuf, W2, msg2, ML_, D_, 512);
    // LN2 + residual
    ln_kernel<<<dim3(ML_), blk, 0, stream>>>(msg2, g2, b2, x, out);
}

// Round 2
// 317.867 us; speedup vs baseline: 1.8796x; 1.8796x over previous
//
#include <hip/hip_runtime.h>
#include <hip/hip_bf16.h>
#include <math.h>

// Problem constants
#define B_  2
#define L_  2048
#define S_  2048
#define D_  256
#define H_  8
#define HD_ 32
#define ML_ (B_ * L_)   // 4096 rows for x-side matmuls
#define MS_ (B_ * S_)   // 4096 rows for source-side matmuls

typedef __attribute__((ext_vector_type(8))) short short8;   // 8 bf16 (A/B frag)
typedef __attribute__((ext_vector_type(4))) float f32x4;    // C/D frag

// ---------------------------------------------------------------------------
// GEMM NT: C[M,N] = A[M,K] @ B[N,K]^T, optional ReLU, templated output type.
// 64x64 tile, BK=16, 256 threads, 4x4/thread, fp32 VALU. (Round-3 MFMA target.)
// ---------------------------------------------------------------------------
template <bool RELU, typename OutT>
__global__ __launch_bounds__(256) void gemm_nt(const float* __restrict__ A,
                                               const float* __restrict__ Bm,
                                               OutT* __restrict__ C,
                                               int M, int N, int K) {
    const int BM = 64, BN = 64, BK = 16;
    __shared__ float As[BK][BM];
    __shared__ float Bs[BK][BN];
    const int tid = threadIdx.x;
    const int tn = tid % 16, tm = tid / 16;
    const int m0 = blockIdx.x * BM, n0 = blockIdx.y * BN;
    float acc[4][4] = {};

    const int r  = tid / 4;
    const int kc = (tid % 4) * 4;

    for (int k0 = 0; k0 < K; k0 += BK) {
        float4 av = *(const float4*)(&A [(size_t)(m0 + r) * K + k0 + kc]);
        float4 bv = *(const float4*)(&Bm[(size_t)(n0 + r) * K + k0 + kc]);
        As[kc + 0][r] = av.x; As[kc + 1][r] = av.y;
        As[kc + 2][r] = av.z; As[kc + 3][r] = av.w;
        Bs[kc + 0][r] = bv.x; Bs[kc + 1][r] = bv.y;
        Bs[kc + 2][r] = bv.z; Bs[kc + 3][r] = bv.w;
        __syncthreads();
#pragma unroll
        for (int k = 0; k < BK; ++k) {
            float4 a4 = *(const float4*)&As[k][tm * 4];
            float4 b4 = *(const float4*)&Bs[k][tn * 4];
            float a[4] = {a4.x, a4.y, a4.z, a4.w};
            float b[4] = {b4.x, b4.y, b4.z, b4.w};
#pragma unroll
            for (int i = 0; i < 4; ++i)
#pragma unroll
                for (int j = 0; j < 4; ++j) acc[i][j] += a[i] * b[j];
        }
        __syncthreads();
    }
#pragma unroll
    for (int i = 0; i < 4; ++i) {
        const int m = m0 + tm * 4 + i;
#pragma unroll
        for (int j = 0; j < 4; ++j) {
            float v = acc[i][j];
            if (RELU) v = fmaxf(v, 0.f);
            C[(size_t)m * N + n0 + tn * 4 + j] = (OutT)v;
        }
    }
}

// ---------------------------------------------------------------------------
// Flash attention, bf16 MFMA (16x16x32). Block = 4 independent waves, no
// __syncthreads. Wave w: 16 q-rows [q0+16w, ..), head = blockIdx.y.
// Q A-frag in regs (loaded once). K/Vt B-frags direct from global (L2-hot).
// P round-trips through wave-private LDS (stride 72 -> bank-capacity optimal).
// Softmax in fp32 on C-layout (row = quad*4+reg, col = lane&15).
// ---------------------------------------------------------------------------
__global__ __launch_bounds__(256) void attn_mfma(const __hip_bfloat16* __restrict__ Qb,
                                                 const __hip_bfloat16* __restrict__ Kb,
                                                 const __hip_bfloat16* __restrict__ Vtb,
                                                 const float* __restrict__ F,
                                                 float* __restrict__ O) {
    const int tid  = threadIdx.x;
    const int w    = tid >> 6;
    const int lane = tid & 63;
    const int colL = lane & 15;
    const int quad = lane >> 4;

    const int b  = blockIdx.z;
    const int h  = blockIdx.y;
    const int qw = blockIdx.x * 64 + w * 16;   // first q-row of this wave

    __shared__ __hip_bfloat16 Pw[4][16][72];   // wave-private P tiles, 9216 B

    // Q A-frag: A[m=colL][k=quad*8+j]
    const short8 aq = *(const short8*)(Qb + ((size_t)(b * L_ + qw + colL)) * D_ + h * HD_ + quad * 8);

    // Per-lane softmax state for rows quad*4 + r
    float m_run[4] = {-INFINITY, -INFINITY, -INFINITY, -INFINITY};
    float l_run[4] = {0.f, 0.f, 0.f, 0.f};
    f32x4 o0 = {0.f, 0.f, 0.f, 0.f}, o1 = {0.f, 0.f, 0.f, 0.f};

    const float scale = 0.17677669529663687f;  // 1/sqrt(32)
    const __hip_bfloat16* kbase  = Kb  + ((size_t)(b * S_ + colL)) * D_ + h * HD_ + quad * 8;
    const __hip_bfloat16* vtbase = Vtb + ((size_t)b) * D_ * S_ + ((size_t)(h * HD_ + colL)) * S_ + quad * 8;
    const float* fbase = F + ((size_t)(b * L_ + qw + quad * 4)) * S_ + colL;

#pragma unroll 1
    for (int s0 = 0; s0 < S_; s0 += 64) {
        // ---- QK^T: 4 n-subtiles of 16 s-cols ----
        f32x4 cc[4];
#pragma unroll
        for (int n = 0; n < 4; ++n) {
            short8 kf = *(const short8*)(kbase + (size_t)(s0 + n * 16) * D_);
            f32x4 z = {0.f, 0.f, 0.f, 0.f};
            cc[n] = __builtin_amdgcn_mfma_f32_16x16x32_bf16(aq, kf, z, 0, 0, 0);
        }
        // ---- F gate + scale (fp32), tile row-max ----
        float tmax[4] = {-INFINITY, -INFINITY, -INFINITY, -INFINITY};
#pragma unroll
        for (int n = 0; n < 4; ++n)
#pragma unroll
            for (int r = 0; r < 4; ++r) {
                float fv = fbase[(size_t)r * S_ + s0 + n * 16];
                float v = cc[n][r] * scale * fv;
                cc[n][r] = v;
                tmax[r] = fmaxf(tmax[r], v);
            }
#pragma unroll
        for (int r = 0; r < 4; ++r) {
            float t = tmax[r];
            t = fmaxf(t, __shfl_xor(t, 1));
            t = fmaxf(t, __shfl_xor(t, 2));
            t = fmaxf(t, __shfl_xor(t, 4));
            t = fmaxf(t, __shfl_xor(t, 8));
            tmax[r] = t;
        }
        float alpha[4];
#pragma unroll
        for (int r = 0; r < 4; ++r) {
            float mn = fmaxf(m_run[r], tmax[r]);
            alpha[r] = __expf(m_run[r] - mn);   // first tile: exp(-inf)=0
            m_run[r] = mn;
            o0[r] *= alpha[r];
            o1[r] *= alpha[r];
        }
        // ---- exp, write P (bf16) to LDS, row-sum ----
        float rsum[4] = {0.f, 0.f, 0.f, 0.f};
#pragma unroll
        for (int n = 0; n < 4; ++n)
#pragma unroll
            for (int r = 0; r < 4; ++r) {
                float p = __expf(cc[n][r] - m_run[r]);
                rsum[r] += p;
                Pw[w][quad * 4 + r][n * 16 + colL] = __float2bfloat16(p);
            }
#pragma unroll
        for (int r = 0; r < 4; ++r) {
            float t = rsum[r];
            t += __shfl_xor(t, 1);
            t += __shfl_xor(t, 2);
            t += __shfl_xor(t, 4);
            t += __shfl_xor(t, 8);
            l_run[r] = l_run[r] * alpha[r] + t;
        }
        // ---- PV: P A-frags from LDS (same-wave, lgkmcnt only), Vt from global ----
        short8 a0 = *(const short8*)(&Pw[w][colL][quad * 8]);
        short8 a1 = *(const short8*)(&Pw[w][colL][32 + quad * 8]);
#pragma unroll
        for (int ks = 0; ks < 2; ++ks) {
            short8 ap = ks ? a1 : a0;
#pragma unroll
            for (int nt = 0; nt < 2; ++nt) {
                short8 vf = *(const short8*)(vtbase + (size_t)nt * 16 * S_ + s0 + ks * 32);
                if (nt == 0) o0 = __builtin_amdgcn_mfma_f32_16x16x32_bf16(ap, vf, o0, 0, 0, 0);
                else         o1 = __builtin_amdgcn_mfma_f32_16x16x32_bf16(ap, vf, o1, 0, 0, 0);
            }
        }
    }

    // ---- epilogue: normalize, store fp32 ----
#pragma unroll
    for (int r = 0; r < 4; ++r) {
        const float inv = 1.f / l_run[r];
        const size_t row = (size_t)(b * L_ + qw + quad * 4 + r);
        O[row * D_ + h * HD_ + colL]      = o0[r] * inv;
        O[row * D_ + h * HD_ + 16 + colL] = o1[r] * inv;
    }
}

// ---------------------------------------------------------------------------
// LayerNorm over D=256; one block per row. Optional residual add.
// ---------------------------------------------------------------------------
__global__ __launch_bounds__(256) void ln_kernel(const float* __restrict__ X,
                                                 const float* __restrict__ g,
                                                 const float* __restrict__ bb,
                                                 const float* __restrict__ addx,
                                                 float* __restrict__ Y) {
    const int row = blockIdx.x;
    const int tid = threadIdx.x;
    const float x = X[(size_t)row * D_ + tid];
    float s = x, q = x * x;
#pragma unroll
    for (int off = 32; off; off >>= 1) {
        s += __shfl_down(s, off);
        q += __shfl_down(q, off);
    }
    __shared__ float rs[4], rq[4];
    const int wid = tid >> 6, lane = tid & 63;
    if (lane == 0) { rs[wid] = s; rq[wid] = q; }
    __syncthreads();
    const float S = rs[0] + rs[1] + rs[2] + rs[3];
    const float Qs = rq[0] + rq[1] + rq[2] + rq[3];
    const float mean = S * (1.f / D_);
    const float var = Qs * (1.f / D_) - mean * mean;
    float y = (x - mean) * rsqrtf(var + 1e-5f) * g[tid] + bb[tid];
    if (addx) y += addx[(size_t)row * D_ + tid];
    Y[(size_t)row * D_ + tid] = y;
}

__global__ __launch_bounds__(256) void concat_kernel(const float* __restrict__ X,
                                                     const float* __restrict__ Mg,
                                                     float* __restrict__ Hc) {
    const int idx = blockIdx.x * 256 + threadIdx.x;
    const int row = idx >> 9;
    const int c = idx & 511;
    Hc[idx] = (c < 256) ? X[(size_t)row * 256 + c] : Mg[(size_t)row * 256 + c - 256];
}

// ---------------------------------------------------------------------------
extern "C" void kernel_launch(void* const* d_in, const int* in_sizes, int n_in,
                              void* d_out, int out_size, void* d_ws, size_t ws_size,
                              hipStream_t stream) {
    (void)in_sizes; (void)n_in; (void)out_size; (void)ws_size;
    const float* x   = (const float*)d_in[0];
    const float* src = (const float*)d_in[1];
    const float* F   = (const float*)d_in[2];
    const float* Wq  = (const float*)d_in[3];
    const float* Wk  = (const float*)d_in[4];
    const float* Wv  = (const float*)d_in[5];
    const float* Wm  = (const float*)d_in[6];
    const float* W1  = (const float*)d_in[7];
    const float* W2  = (const float*)d_in[8];
    const float* g1  = (const float*)d_in[9];
    const float* b1  = (const float*)d_in[10];
    const float* g2  = (const float*)d_in[11];
    const float* b2  = (const float*)d_in[12];
    float* out = (float*)d_out;

    // Workspace layout (bytes), 24 MB total, aliased:
    //   [0,2M)   Qb (bf16)      -> msg/msg2 region [0,4M) after attention
    //   [2M,4M)  Kb (bf16)
    //   [4M,6M)  Vtb (bf16)     -> m1 region [4M,8M) after attention
    //   [6M,10M) o (fp32)
    //   [8M,16M) hcat           (o dead after Wm-GEMM)
    //   [16M,24M) hbuf
    char* ws = (char*)d_ws;
    __hip_bfloat16* Qb  = (__hip_bfloat16*)(ws);
    __hip_bfloat16* Kb  = (__hip_bfloat16*)(ws + (2 << 20));
    __hip_bfloat16* Vtb = (__hip_bfloat16*)(ws + (4 << 20));
    float* o    = (float*)(ws + (6 << 20));
    float* msg  = (float*)(ws);               // over dead Qb/Kb
    float* m1   = (float*)(ws + (4 << 20));   // over dead Vtb
    float* hcat = (float*)(ws + (8 << 20));   // over dead o (after Wm gemm)
    float* hbuf = (float*)(ws + (16 << 20));
    float* msg2 = (float*)(ws);

    dim3 blk(256);
    // Projections: Q,K -> bf16 [rows][256]; V -> transposed bf16 [b][256][2048]
    gemm_nt<false, __hip_bfloat16><<<dim3(ML_ / 64, D_ / 64), blk, 0, stream>>>(x,   Wq, Qb, ML_, D_, D_);
    gemm_nt<false, __hip_bfloat16><<<dim3(MS_ / 64, D_ / 64), blk, 0, stream>>>(src, Wk, Kb, MS_, D_, D_);
    for (int b = 0; b < B_; ++b)
        gemm_nt<false, __hip_bfloat16><<<dim3(D_ / 64, S_ / 64), blk, 0, stream>>>(
            Wv, src + (size_t)b * S_ * D_, Vtb + (size_t)b * D_ * S_, D_, S_, D_);
    // Attention (bf16 MFMA flash)
    attn_mfma<<<dim3(L_ / 64, H_, B_), blk, 0, stream>>>(Qb, Kb, Vtb, F, o);
    // Out-proj + LN1
    gemm_nt<false, float><<<dim3(ML_ / 64, D_ / 64), blk, 0, stream>>>(o, Wm, msg, ML_, D_, D_);
    ln_kernel<<<dim3(ML_), blk, 0, stream>>>(msg, g1, b1, nullptr, m1);
    // MLP
    concat_kernel<<<dim3(ML_ * 512 / 256), blk, 0, stream>>>(x, m1, hcat);
    gemm_nt<true,  float><<<dim3(ML_ / 64, 512 / 64), blk, 0, stream>>>(hcat, W1, hbuf, ML_, 512, 512);
    gemm_nt<false, float><<<dim3(ML_ / 64, D_ / 64), blk, 0, stream>>>(hbuf, W2, msg2, ML_, D_, 512);
    // LN2 + residual
    ln_kernel<<<dim3(ML_), blk, 0, stream>>>(msg2, g2, b2, x, out);
}

// Round 4
// 238.596 us; speedup vs baseline: 2.5041x; 1.3322x over previous
//
#include <hip/hip_runtime.h>
#include <hip/hip_bf16.h>
#include <math.h>

// Problem constants
#define B_  2
#define L_  2048
#define S_  2048
#define D_  256
#define H_  8
#define HD_ 32
#define ML_ (B_ * L_)
#define MS_ (B_ * S_)

typedef __attribute__((ext_vector_type(8))) short short8;   // 8 bf16 (A/B frag)
typedef __attribute__((ext_vector_type(4))) float f32x4;    // C/D frag

// ---------------------------------------------------------------------------
// One-shot fp32 -> bf16 conversion of all GEMM operands (x, source, 6 weights).
// ---------------------------------------------------------------------------
__global__ __launch_bounds__(256) void convert_all(
    const float* __restrict__ x,  const float* __restrict__ src,
    const float* __restrict__ Wq, const float* __restrict__ Wk,
    const float* __restrict__ Wv, const float* __restrict__ Wm,
    const float* __restrict__ W1, const float* __restrict__ W2,
    __hip_bfloat16* xb,  __hip_bfloat16* srcb,
    __hip_bfloat16* Wqb, __hip_bfloat16* Wkb,
    __hip_bfloat16* Wvb, __hip_bfloat16* Wmb,
    __hip_bfloat16* W1b, __hip_bfloat16* W2b) {
    const size_t i4 = ((size_t)blockIdx.x * 256 + threadIdx.x) * 4;
    const float* sp; __hip_bfloat16* dp; size_t off;
    if      (i4 < 1048576) { sp = x;   dp = xb;   off = i4; }
    else if (i4 < 2097152) { sp = src; dp = srcb; off = i4 - 1048576; }
    else if (i4 < 2162688) { sp = Wq;  dp = Wqb;  off = i4 - 2097152; }
    else if (i4 < 2228224) { sp = Wk;  dp = Wkb;  off = i4 - 2162688; }
    else if (i4 < 2293760) { sp = Wv;  dp = Wvb;  off = i4 - 2228224; }
    else if (i4 < 2359296) { sp = Wm;  dp = Wmb;  off = i4 - 2293760; }
    else if (i4 < 2621440) { sp = W1;  dp = W1b;  off = i4 - 2359296; }
    else                   { sp = W2;  dp = W2b;  off = i4 - 2621440; }
    float4 v = *(const float4*)(sp + off);
    __hip_bfloat16 o0 = __float2bfloat16(v.x), o1 = __float2bfloat16(v.y);
    __hip_bfloat16 o2 = __float2bfloat16(v.z), o3 = __float2bfloat16(v.w);
    __hip_bfloat16* d = dp + off;
    d[0] = o0; d[1] = o1; d[2] = o2; d[3] = o3;
}

// ---------------------------------------------------------------------------
// bf16 MFMA GEMM NT: C[M,N] = A[M,K] @ B[N,K]^T. 64x64 tile, BK=64,
// 256 thr = 4 waves, each wave 32x32 via 2x2 16x16x32 MFMA frags.
// A2: optional second A source for k >= 256 (fused concat for W1 GEMM).
// lda: row stride of A AND A2 (256 for the split-concat case; else == K).
// LDS rows padded to 72 bf16.
// ---------------------------------------------------------------------------
template <bool RELU, typename OutT>
__global__ __launch_bounds__(256) void gemm_bf16(const __hip_bfloat16* __restrict__ A,
                                                 const __hip_bfloat16* __restrict__ A2,
                                                 const __hip_bfloat16* __restrict__ Bm,
                                                 OutT* __restrict__ C,
                                                 int M, int N, int K, int lda) {
    __shared__ __hip_bfloat16 As[64][72];
    __shared__ __hip_bfloat16 Bs[64][72];
    const int tid  = threadIdx.x;
    const int w    = tid >> 6;
    const int lane = tid & 63;
    const int colL = lane & 15;
    const int quad = lane >> 4;
    const int m0 = blockIdx.x * 64, n0 = blockIdx.y * 64;
    const int mh = (w & 1) * 32, nh = (w >> 1) * 32;

    const int srow = tid >> 3;          // 0..31, two passes -> 64 rows
    const int scg  = (tid & 7) * 8;     // col group (8 bf16 = 16 B)

    f32x4 acc[2][2] = {};

    for (int k0 = 0; k0 < K; k0 += 64) {
        const __hip_bfloat16* Asrc = A;
        int kk = k0;
        if (A2 && k0 >= 256) { Asrc = A2; kk = k0 - 256; }
        __syncthreads();
#pragma unroll
        for (int p = 0; p < 2; ++p) {
            const int r = srow + p * 32;
            *(short8*)&As[r][scg] = *(const short8*)(Asrc + (size_t)(m0 + r) * lda + kk + scg);
            *(short8*)&Bs[r][scg] = *(const short8*)(Bm   + (size_t)(n0 + r) * K  + k0 + scg);
        }
        __syncthreads();
#pragma unroll
        for (int ks = 0; ks < 2; ++ks) {
            short8 af[2], bf[2];
#pragma unroll
            for (int i = 0; i < 2; ++i)
                af[i] = *(const short8*)&As[mh + i * 16 + colL][ks * 32 + quad * 8];
#pragma unroll
            for (int j = 0; j < 2; ++j)
                bf[j] = *(const short8*)&Bs[nh + j * 16 + colL][ks * 32 + quad * 8];
#pragma unroll
            for (int i = 0; i < 2; ++i)
#pragma unroll
                for (int j = 0; j < 2; ++j)
                    acc[i][j] = __builtin_amdgcn_mfma_f32_16x16x32_bf16(af[i], bf[j], acc[i][j], 0, 0, 0);
        }
    }
#pragma unroll
    for (int i = 0; i < 2; ++i)
#pragma unroll
        for (int r = 0; r < 4; ++r) {
            const size_t row = m0 + mh + i * 16 + quad * 4 + r;
#pragma unroll
            for (int j = 0; j < 2; ++j) {
                float v = acc[i][j][r];
                if (RELU) v = fmaxf(v, 0.f);
                C[row * N + n0 + nh + j * 16 + colL] = (OutT)v;
            }
        }
}

// ---------------------------------------------------------------------------
// Flash attention, bf16 MFMA (16x16x32). O written as bf16.
// ---------------------------------------------------------------------------
__global__ __launch_bounds__(256) void attn_mfma(const __hip_bfloat16* __restrict__ Qb,
                                                 const __hip_bfloat16* __restrict__ Kb,
                                                 const __hip_bfloat16* __restrict__ Vtb,
                                                 const float* __restrict__ F,
                                                 __hip_bfloat16* __restrict__ O) {
    const int tid  = threadIdx.x;
    const int w    = tid >> 6;
    const int lane = tid & 63;
    const int colL = lane & 15;
    const int quad = lane >> 4;

    const int b  = blockIdx.z;
    const int h  = blockIdx.y;
    const int qw = blockIdx.x * 64 + w * 16;

    __shared__ __hip_bfloat16 Pw[4][16][72];

    const short8 aq = *(const short8*)(Qb + ((size_t)(b * L_ + qw + colL)) * D_ + h * HD_ + quad * 8);

    float m_run[4] = {-INFINITY, -INFINITY, -INFINITY, -INFINITY};
    float l_run[4] = {0.f, 0.f, 0.f, 0.f};
    f32x4 o0 = {0.f, 0.f, 0.f, 0.f}, o1 = {0.f, 0.f, 0.f, 0.f};

    const float scale = 0.17677669529663687f;
    const __hip_bfloat16* kbase  = Kb  + ((size_t)(b * S_ + colL)) * D_ + h * HD_ + quad * 8;
    const __hip_bfloat16* vtbase = Vtb + ((size_t)b) * D_ * S_ + ((size_t)(h * HD_ + colL)) * S_ + quad * 8;
    const float* fbase = F + ((size_t)(b * L_ + qw + quad * 4)) * S_ + colL;

#pragma unroll 1
    for (int s0 = 0; s0 < S_; s0 += 64) {
        f32x4 cc[4];
#pragma unroll
        for (int n = 0; n < 4; ++n) {
            short8 kf = *(const short8*)(kbase + (size_t)(s0 + n * 16) * D_);
            f32x4 z = {0.f, 0.f, 0.f, 0.f};
            cc[n] = __builtin_amdgcn_mfma_f32_16x16x32_bf16(aq, kf, z, 0, 0, 0);
        }
        float tmax[4] = {-INFINITY, -INFINITY, -INFINITY, -INFINITY};
#pragma unroll
        for (int n = 0; n < 4; ++n)
#pragma unroll
            for (int r = 0; r < 4; ++r) {
                float fv = fbase[(size_t)r * S_ + s0 + n * 16];
                float v = cc[n][r] * scale * fv;
                cc[n][r] = v;
                tmax[r] = fmaxf(tmax[r], v);
            }
#pragma unroll
        for (int r = 0; r < 4; ++r) {
            float t = tmax[r];
            t = fmaxf(t, __shfl_xor(t, 1));
            t = fmaxf(t, __shfl_xor(t, 2));
            t = fmaxf(t, __shfl_xor(t, 4));
            t = fmaxf(t, __shfl_xor(t, 8));
            tmax[r] = t;
        }
        float alpha[4];
#pragma unroll
        for (int r = 0; r < 4; ++r) {
            float mn = fmaxf(m_run[r], tmax[r]);
            alpha[r] = __expf(m_run[r] - mn);
            m_run[r] = mn;
            o0[r] *= alpha[r];
            o1[r] *= alpha[r];
        }
        float rsum[4] = {0.f, 0.f, 0.f, 0.f};
#pragma unroll
        for (int n = 0; n < 4; ++n)
#pragma unroll
            for (int r = 0; r < 4; ++r) {
                float p = __expf(cc[n][r] - m_run[r]);
                rsum[r] += p;
                Pw[w][quad * 4 + r][n * 16 + colL] = __float2bfloat16(p);
            }
#pragma unroll
        for (int r = 0; r < 4; ++r) {
            float t = rsum[r];
            t += __shfl_xor(t, 1);
            t += __shfl_xor(t, 2);
            t += __shfl_xor(t, 4);
            t += __shfl_xor(t, 8);
            l_run[r] = l_run[r] * alpha[r] + t;
        }
        short8 a0 = *(const short8*)(&Pw[w][colL][quad * 8]);
        short8 a1 = *(const short8*)(&Pw[w][colL][32 + quad * 8]);
#pragma unroll
        for (int ks = 0; ks < 2; ++ks) {
            short8 ap = ks ? a1 : a0;
#pragma unroll
            for (int nt = 0; nt < 2; ++nt) {
                short8 vf = *(const short8*)(vtbase + (size_t)nt * 16 * S_ + s0 + ks * 32);
                if (nt == 0) o0 = __builtin_amdgcn_mfma_f32_16x16x32_bf16(ap, vf, o0, 0, 0, 0);
                else         o1 = __builtin_amdgcn_mfma_f32_16x16x32_bf16(ap, vf, o1, 0, 0, 0);
            }
        }
    }

#pragma unroll
    for (int r = 0; r < 4; ++r) {
        const float inv = 1.f / l_run[r];
        const size_t row = (size_t)(b * L_ + qw + quad * 4 + r);
        O[row * D_ + h * HD_ + colL]      = __float2bfloat16(o0[r] * inv);
        O[row * D_ + h * HD_ + 16 + colL] = __float2bfloat16(o1[r] * inv);
    }
}

// ---------------------------------------------------------------------------
// LayerNorm over D=256, one block per row.
// ---------------------------------------------------------------------------
__device__ __forceinline__ float ln_stat(float x, float* rs, float* rq,
                                         int tid, float* mean_out, float* rstd_out) {
    float s = x, q = x * x;
#pragma unroll
    for (int off = 32; off; off >>= 1) {
        s += __shfl_down(s, off);
        q += __shfl_down(q, off);
    }
    const int wid = tid >> 6, lane = tid & 63;
    if (lane == 0) { rs[wid] = s; rq[wid] = q; }
    __syncthreads();
    const float S = rs[0] + rs[1] + rs[2] + rs[3];
    const float Q = rq[0] + rq[1] + rq[2] + rq[3];
    const float mean = S * (1.f / D_);
    const float var = Q * (1.f / D_) - mean * mean;
    *mean_out = mean;
    *rstd_out = rsqrtf(var + 1e-5f);
    return x;
}

__global__ __launch_bounds__(256) void ln_to_bf16(const float* __restrict__ X,
                                                  const float* __restrict__ g,
                                                  const float* __restrict__ bb,
                                                  __hip_bfloat16* __restrict__ Y) {
    const int row = blockIdx.x, tid = threadIdx.x;
    __shared__ float rs[4], rq[4];
    float mean, rstd;
    const float x = ln_stat(X[(size_t)row * D_ + tid], rs, rq, tid, &mean, &rstd);
    Y[(size_t)row * D_ + tid] = __float2bfloat16((x - mean) * rstd * g[tid] + bb[tid]);
}

__global__ __launch_bounds__(256) void ln_residual(const float* __restrict__ X,
                                                   const float* __restrict__ g,
                                                   const float* __restrict__ bb,
                                                   const float* __restrict__ addx,
                                                   float* __restrict__ Y) {
    const int row = blockIdx.x, tid = threadIdx.x;
    __shared__ float rs[4], rq[4];
    float mean, rstd;
    const float x = ln_stat(X[(size_t)row * D_ + tid], rs, rq, tid, &mean, &rstd);
    Y[(size_t)row * D_ + tid] = (x - mean) * rstd * g[tid] + bb[tid] + addx[(size_t)row * D_ + tid];
}

// ---------------------------------------------------------------------------
extern "C" void kernel_launch(void* const* d_in, const int* in_sizes, int n_in,
                              void* d_out, int out_size, void* d_ws, size_t ws_size,
                              hipStream_t stream) {
    (void)in_sizes; (void)n_in; (void)out_size; (void)ws_size;
    const float* x   = (const float*)d_in[0];
    const float* src = (const float*)d_in[1];
    const float* F   = (const float*)d_in[2];
    const float* Wq  = (const float*)d_in[3];
    const float* Wk  = (const float*)d_in[4];
    const float* Wv  = (const float*)d_in[5];
    const float* Wm  = (const float*)d_in[6];
    const float* W1  = (const float*)d_in[7];
    const float* W2  = (const float*)d_in[8];
    const float* g1  = (const float*)d_in[9];
    const float* b1  = (const float*)d_in[10];
    const float* g2  = (const float*)d_in[11];
    const float* b2  = (const float*)d_in[12];
    float* out = (float*)d_out;

    // Workspace (24 MB):
    //   [0,2M)    x_b     [2M,4M)  src_b
    //   [4M,5.25M) weights bf16: Wq,Wk,Wv,Wm (128K each), W1 (512K), W2 (256K)
    //   [6M,8M)   Qb   [8M,10M) Kb   [10M,12M) Vtb   [12M,14M) o_b
    //   [14M,18M) msg fp32 (reused as msg2)
    //   [18M,20M) m1_b   [20M,24M) h_b
    char* ws = (char*)d_ws;
    __hip_bfloat16* x_b   = (__hip_bfloat16*)(ws);
    __hip_bfloat16* src_b = (__hip_bfloat16*)(ws + (2u << 20));
    __hip_bfloat16* Wq_b  = (__hip_bfloat16*)(ws + (4u << 20));
    __hip_bfloat16* Wk_b  = (__hip_bfloat16*)(ws + (4u << 20) + 131072);
    __hip_bfloat16* Wv_b  = (__hip_bfloat16*)(ws + (4u << 20) + 2 * 131072);
    __hip_bfloat16* Wm_b  = (__hip_bfloat16*)(ws + (4u << 20) + 3 * 131072);
    __hip_bfloat16* W1_b  = (__hip_bfloat16*)(ws + (4u << 20) + 4 * 131072);
    __hip_bfloat16* W2_b  = (__hip_bfloat16*)(ws + (4u << 20) + 4 * 131072 + 524288);
    __hip_bfloat16* Qb  = (__hip_bfloat16*)(ws + (6u << 20));
    __hip_bfloat16* Kb  = (__hip_bfloat16*)(ws + (8u << 20));
    __hip_bfloat16* Vtb = (__hip_bfloat16*)(ws + (10u << 20));
    __hip_bfloat16* o_b = (__hip_bfloat16*)(ws + (12u << 20));
    float* msg  = (float*)(ws + (14u << 20));
    __hip_bfloat16* m1_b = (__hip_bfloat16*)(ws + (18u << 20));
    __hip_bfloat16* h_b  = (__hip_bfloat16*)(ws + (20u << 20));

    dim3 blk(256);
    convert_all<<<dim3(2688), blk, 0, stream>>>(x, src, Wq, Wk, Wv, Wm, W1, W2,
                                                x_b, src_b, Wq_b, Wk_b, Wv_b, Wm_b, W1_b, W2_b);
    // Projections (bf16 MFMA)
    gemm_bf16<false, __hip_bfloat16><<<dim3(ML_ / 64, D_ / 64), blk, 0, stream>>>(x_b,   nullptr, Wq_b, Qb, ML_, D_, D_, D_);
    gemm_bf16<false, __hip_bfloat16><<<dim3(MS_ / 64, D_ / 64), blk, 0, stream>>>(src_b, nullptr, Wk_b, Kb, MS_, D_, D_, D_);
    for (int b = 0; b < B_; ++b)
        gemm_bf16<false, __hip_bfloat16><<<dim3(D_ / 64, S_ / 64), blk, 0, stream>>>(
            Wv_b, nullptr, src_b + (size_t)b * S_ * D_, Vtb + (size_t)b * D_ * S_, D_, S_, D_, D_);
    // Attention
    attn_mfma<<<dim3(L_ / 64, H_, B_), blk, 0, stream>>>(Qb, Kb, Vtb, F, o_b);
    // Out-proj + LN1 (bf16 out)
    gemm_bf16<false, float><<<dim3(ML_ / 64, D_ / 64), blk, 0, stream>>>(o_b, nullptr, Wm_b, msg, ML_, D_, D_, D_);
    ln_to_bf16<<<dim3(ML_), blk, 0, stream>>>(msg, g1, b1, m1_b);
    // MLP: W1 GEMM reads A split: x_b (k<256) / m1_b (k>=256), both lda=256
    gemm_bf16<true,  __hip_bfloat16><<<dim3(ML_ / 64, 512 / 64), blk, 0, stream>>>(x_b, m1_b, W1_b, h_b, ML_, 512, 512, 256);
    gemm_bf16<false, float><<<dim3(ML_ / 64, D_ / 64), blk, 0, stream>>>(h_b, nullptr, W2_b, msg, ML_, D_, 512, 512);
    // LN2 + residual
    ln_residual<<<dim3(ML_), blk, 0, stream>>>(msg, g2, b2, x, out);
}

// Round 5
// 237.830 us; speedup vs baseline: 2.5121x; 1.0032x over previous
//
#include <hip/hip_runtime.h>
#include <hip/hip_bf16.h>
#include <math.h>

// Problem constants
#define B_  2
#define L_  2048
#define S_  2048
#define D_  256
#define H_  8
#define HD_ 32
#define ML_ (B_ * L_)
#define MS_ (B_ * S_)
#define NSPLIT 4
#define SCHUNK (S_ / NSPLIT)   // 512

typedef __attribute__((ext_vector_type(8))) short short8;   // 8 bf16 (A/B frag)
typedef __attribute__((ext_vector_type(4))) float f32x4;    // C/D frag

// ---------------------------------------------------------------------------
// One-shot fp32 -> bf16 conversion of all GEMM operands.
// ---------------------------------------------------------------------------
__global__ __launch_bounds__(256) void convert_all(
    const float* __restrict__ x,  const float* __restrict__ src,
    const float* __restrict__ Wq, const float* __restrict__ Wk,
    const float* __restrict__ Wv, const float* __restrict__ Wm,
    const float* __restrict__ W1, const float* __restrict__ W2,
    __hip_bfloat16* xb,  __hip_bfloat16* srcb,
    __hip_bfloat16* Wqb, __hip_bfloat16* Wkb,
    __hip_bfloat16* Wvb, __hip_bfloat16* Wmb,
    __hip_bfloat16* W1b, __hip_bfloat16* W2b) {
    const size_t i4 = ((size_t)blockIdx.x * 256 + threadIdx.x) * 4;
    const float* sp; __hip_bfloat16* dp; size_t off;
    if      (i4 < 1048576) { sp = x;   dp = xb;   off = i4; }
    else if (i4 < 2097152) { sp = src; dp = srcb; off = i4 - 1048576; }
    else if (i4 < 2162688) { sp = Wq;  dp = Wqb;  off = i4 - 2097152; }
    else if (i4 < 2228224) { sp = Wk;  dp = Wkb;  off = i4 - 2162688; }
    else if (i4 < 2293760) { sp = Wv;  dp = Wvb;  off = i4 - 2228224; }
    else if (i4 < 2359296) { sp = Wm;  dp = Wmb;  off = i4 - 2293760; }
    else if (i4 < 2621440) { sp = W1;  dp = W1b;  off = i4 - 2359296; }
    else                   { sp = W2;  dp = W2b;  off = i4 - 2621440; }
    float4 v = *(const float4*)(sp + off);
    __hip_bfloat16 o0 = __float2bfloat16(v.x), o1 = __float2bfloat16(v.y);
    __hip_bfloat16 o2 = __float2bfloat16(v.z), o3 = __float2bfloat16(v.w);
    __hip_bfloat16* d = dp + off;
    d[0] = o0; d[1] = o1; d[2] = o2; d[3] = o3;
}

// ---------------------------------------------------------------------------
// Shared bf16 MFMA GEMM body: C tile [m0:m0+64, n0:n0+64] of A[.,K]@Bm[N,K]^T.
// Register prefetch of next k-tile across the barrier (lite double-buffer).
// A2: second A source for k>=256 (fused concat); lda = row stride of A/A2.
// ---------------------------------------------------------------------------
template <bool RELU, typename OutT>
__device__ __forceinline__ void gemm_body(const __hip_bfloat16* __restrict__ A,
                                          const __hip_bfloat16* __restrict__ A2,
                                          const __hip_bfloat16* __restrict__ Bm,
                                          OutT* __restrict__ C,
                                          int N, int K, int lda, int m0, int n0,
                                          __hip_bfloat16 (&As)[64][72],
                                          __hip_bfloat16 (&Bs)[64][72]) {
    const int tid  = threadIdx.x;
    const int w    = tid >> 6;
    const int lane = tid & 63;
    const int colL = lane & 15;
    const int quad = lane >> 4;
    const int mh = (w & 1) * 32, nh = (w >> 1) * 32;
    const int srow = tid >> 3;          // 0..31, two passes -> 64 rows
    const int scg  = (tid & 7) * 8;     // col group (8 bf16 = 16 B)

    f32x4 acc[2][2] = {};

    auto loadA = [&](int p, int k0) -> short8 {
        const __hip_bfloat16* Asrc = A; int kk = k0;
        if (A2 && k0 >= 256) { Asrc = A2; kk = k0 - 256; }
        return *(const short8*)(Asrc + (size_t)(m0 + srow + p * 32) * lda + kk + scg);
    };
    auto loadB = [&](int p, int k0) -> short8 {
        return *(const short8*)(Bm + (size_t)(n0 + srow + p * 32) * K + k0 + scg);
    };

    short8 ra[2], rb[2];
#pragma unroll
    for (int p = 0; p < 2; ++p) { ra[p] = loadA(p, 0); rb[p] = loadB(p, 0); }

    for (int k0 = 0; k0 < K; k0 += 64) {
        __syncthreads();
#pragma unroll
        for (int p = 0; p < 2; ++p) {
            *(short8*)&As[srow + p * 32][scg] = ra[p];
            *(short8*)&Bs[srow + p * 32][scg] = rb[p];
        }
        __syncthreads();
        if (k0 + 64 < K) {
#pragma unroll
            for (int p = 0; p < 2; ++p) { ra[p] = loadA(p, k0 + 64); rb[p] = loadB(p, k0 + 64); }
        }
#pragma unroll
        for (int ks = 0; ks < 2; ++ks) {
            short8 af[2], bf[2];
#pragma unroll
            for (int i = 0; i < 2; ++i)
                af[i] = *(const short8*)&As[mh + i * 16 + colL][ks * 32 + quad * 8];
#pragma unroll
            for (int j = 0; j < 2; ++j)
                bf[j] = *(const short8*)&Bs[nh + j * 16 + colL][ks * 32 + quad * 8];
#pragma unroll
            for (int i = 0; i < 2; ++i)
#pragma unroll
                for (int j = 0; j < 2; ++j)
                    acc[i][j] = __builtin_amdgcn_mfma_f32_16x16x32_bf16(af[i], bf[j], acc[i][j], 0, 0, 0);
        }
    }
#pragma unroll
    for (int i = 0; i < 2; ++i)
#pragma unroll
        for (int r = 0; r < 4; ++r) {
            const size_t row = m0 + mh + i * 16 + quad * 4 + r;
#pragma unroll
            for (int j = 0; j < 2; ++j) {
                float v = acc[i][j][r];
                if (RELU) v = fmaxf(v, 0.f);
                C[row * N + n0 + nh + j * 16 + colL] = (OutT)v;
            }
        }
}

template <bool RELU, typename OutT>
__global__ __launch_bounds__(256) void gemm_bf16(const __hip_bfloat16* __restrict__ A,
                                                 const __hip_bfloat16* __restrict__ A2,
                                                 const __hip_bfloat16* __restrict__ Bm,
                                                 OutT* __restrict__ C,
                                                 int N, int K, int lda) {
    __shared__ __hip_bfloat16 As[64][72];
    __shared__ __hip_bfloat16 Bs[64][72];
    gemm_body<RELU, OutT>(A, A2, Bm, C, N, K, lda,
                          blockIdx.x * 64, blockIdx.y * 64, As, Bs);
}

// ---------------------------------------------------------------------------
// Fused Q/K/Vt projection GEMMs in one launch (1024 blocks -> 3 waves/SIMD).
//   id [0,256):    Qb  = x_b   @ Wq^T   (M=4096, N=256)
//   id [256,512):  Kb  = src_b @ Wk^T   (M=4096, N=256)
//   id [512,1024): Vtb[b] = Wv_b @ src_b[b]^T  (M=256, N=2048), b = bit 7
// ---------------------------------------------------------------------------
__global__ __launch_bounds__(256) void proj_fused(const __hip_bfloat16* __restrict__ x_b,
                                                  const __hip_bfloat16* __restrict__ src_b,
                                                  const __hip_bfloat16* __restrict__ Wq_b,
                                                  const __hip_bfloat16* __restrict__ Wk_b,
                                                  const __hip_bfloat16* __restrict__ Wv_b,
                                                  __hip_bfloat16* __restrict__ Qb,
                                                  __hip_bfloat16* __restrict__ Kb,
                                                  __hip_bfloat16* __restrict__ Vtb) {
    __shared__ __hip_bfloat16 As[64][72];
    __shared__ __hip_bfloat16 Bs[64][72];
    const int id = blockIdx.x;
    if (id < 256) {
        gemm_body<false, __hip_bfloat16>(x_b, nullptr, Wq_b, Qb, 256, 256, 256,
                                         (id >> 2) * 64, (id & 3) * 64, As, Bs);
    } else if (id < 512) {
        const int t = id - 256;
        gemm_body<false, __hip_bfloat16>(src_b, nullptr, Wk_b, Kb, 256, 256, 256,
                                         (t >> 2) * 64, (t & 3) * 64, As, Bs);
    } else {
        const int t = id - 512;
        const int b = t >> 7, u = t & 127;
        gemm_body<false, __hip_bfloat16>(Wv_b, nullptr, src_b + (size_t)b * S_ * D_,
                                         Vtb + (size_t)b * D_ * S_, S_, 256, 256,
                                         (u & 3) * 64, (u >> 2) * 64, As, Bs);
    }
}

// ---------------------------------------------------------------------------
// Flash attention, bf16 MFMA, split-S (NSPLIT partials for occupancy).
// Writes unnormalized O partial (bf16) + per-(row,head) m,l (fp32).
// blockIdx.z = b * NSPLIT + split.
// ---------------------------------------------------------------------------
__global__ __launch_bounds__(256, 8) void attn_mfma(const __hip_bfloat16* __restrict__ Qb,
                                                    const __hip_bfloat16* __restrict__ Kb,
                                                    const __hip_bfloat16* __restrict__ Vtb,
                                                    const float* __restrict__ F,
                                                    __hip_bfloat16* __restrict__ Op,
                                                    float* __restrict__ Ml,
                                                    float* __restrict__ Ll) {
    const int tid  = threadIdx.x;
    const int w    = tid >> 6;
    const int lane = tid & 63;
    const int colL = lane & 15;
    const int quad = lane >> 4;

    const int b     = blockIdx.z >> 2;
    const int split = blockIdx.z & 3;
    const int h     = blockIdx.y;
    const int qw    = blockIdx.x * 64 + w * 16;

    __shared__ __hip_bfloat16 Pw[4][16][72];

    const short8 aq = *(const short8*)(Qb + ((size_t)(b * L_ + qw + colL)) * D_ + h * HD_ + quad * 8);

    float m_run[4] = {-INFINITY, -INFINITY, -INFINITY, -INFINITY};
    float l_run[4] = {0.f, 0.f, 0.f, 0.f};
    f32x4 o0 = {0.f, 0.f, 0.f, 0.f}, o1 = {0.f, 0.f, 0.f, 0.f};

    const float scale = 0.17677669529663687f;
    const __hip_bfloat16* kbase  = Kb  + ((size_t)(b * S_ + colL)) * D_ + h * HD_ + quad * 8;
    const __hip_bfloat16* vtbase = Vtb + ((size_t)b) * D_ * S_ + ((size_t)(h * HD_ + colL)) * S_ + quad * 8;
    const float* fbase = F + ((size_t)(b * L_ + qw + quad * 4)) * S_ + colL;

    const int send = split * SCHUNK + SCHUNK;
#pragma unroll 1
    for (int s0 = split * SCHUNK; s0 < send; s0 += 64) {
        f32x4 cc[4];
#pragma unroll
        for (int n = 0; n < 4; ++n) {
            short8 kf = *(const short8*)(kbase + (size_t)(s0 + n * 16) * D_);
            f32x4 z = {0.f, 0.f, 0.f, 0.f};
            cc[n] = __builtin_amdgcn_mfma_f32_16x16x32_bf16(aq, kf, z, 0, 0, 0);
        }
        float tmax[4] = {-INFINITY, -INFINITY, -INFINITY, -INFINITY};
#pragma unroll
        for (int n = 0; n < 4; ++n)
#pragma unroll
            for (int r = 0; r < 4; ++r) {
                float fv = fbase[(size_t)r * S_ + s0 + n * 16];
                float v = cc[n][r] * scale * fv;
                cc[n][r] = v;
                tmax[r] = fmaxf(tmax[r], v);
            }
#pragma unroll
        for (int r = 0; r < 4; ++r) {
            float t = tmax[r];
            t = fmaxf(t, __shfl_xor(t, 1));
            t = fmaxf(t, __shfl_xor(t, 2));
            t = fmaxf(t, __shfl_xor(t, 4));
            t = fmaxf(t, __shfl_xor(t, 8));
            tmax[r] = t;
        }
        float alpha[4];
#pragma unroll
        for (int r = 0; r < 4; ++r) {
            float mn = fmaxf(m_run[r], tmax[r]);
            alpha[r] = __expf(m_run[r] - mn);
            m_run[r] = mn;
            o0[r] *= alpha[r];
            o1[r] *= alpha[r];
        }
        float rsum[4] = {0.f, 0.f, 0.f, 0.f};
#pragma unroll
        for (int n = 0; n < 4; ++n)
#pragma unroll
            for (int r = 0; r < 4; ++r) {
                float p = __expf(cc[n][r] - m_run[r]);
                rsum[r] += p;
                Pw[w][quad * 4 + r][n * 16 + colL] = __float2bfloat16(p);
            }
#pragma unroll
        for (int r = 0; r < 4; ++r) {
            float t = rsum[r];
            t += __shfl_xor(t, 1);
            t += __shfl_xor(t, 2);
            t += __shfl_xor(t, 4);
            t += __shfl_xor(t, 8);
            l_run[r] = l_run[r] * alpha[r] + t;
        }
        short8 a0 = *(const short8*)(&Pw[w][colL][quad * 8]);
        short8 a1 = *(const short8*)(&Pw[w][colL][32 + quad * 8]);
#pragma unroll
        for (int ks = 0; ks < 2; ++ks) {
            short8 ap = ks ? a1 : a0;
#pragma unroll
            for (int nt = 0; nt < 2; ++nt) {
                short8 vf = *(const short8*)(vtbase + (size_t)nt * 16 * S_ + s0 + ks * 32);
                if (nt == 0) o0 = __builtin_amdgcn_mfma_f32_16x16x32_bf16(ap, vf, o0, 0, 0, 0);
                else         o1 = __builtin_amdgcn_mfma_f32_16x16x32_bf16(ap, vf, o1, 0, 0, 0);
            }
        }
    }

    // Partial epilogue: unnormalized O (bf16) + m,l per (row, head).
#pragma unroll
    for (int r = 0; r < 4; ++r) {
        const size_t row = (size_t)(b * L_ + qw + quad * 4 + r);
        const size_t po = ((size_t)split * ML_ + row) * D_ + h * HD_;
        Op[po + colL]      = __float2bfloat16(o0[r]);
        Op[po + 16 + colL] = __float2bfloat16(o1[r]);
        if (colL == 0) {
            Ml[((size_t)split * ML_ + row) * H_ + h] = m_run[r];
            Ll[((size_t)split * ML_ + row) * H_ + h] = l_run[r];
        }
    }
}

// ---------------------------------------------------------------------------
// Combine NSPLIT partials -> normalized o_b (bf16).
// ---------------------------------------------------------------------------
__global__ __launch_bounds__(256) void attn_combine(const __hip_bfloat16* __restrict__ Op,
                                                    const float* __restrict__ Ml,
                                                    const float* __restrict__ Ll,
                                                    __hip_bfloat16* __restrict__ o_b) {
    const int idx = blockIdx.x * 256 + threadIdx.x;   // over ML_*D_
    const int row = idx >> 8, d = idx & 255, h = d >> 5;
    float m[NSPLIT];
    float mmax = -INFINITY;
#pragma unroll
    for (int s = 0; s < NSPLIT; ++s) {
        m[s] = Ml[((size_t)s * ML_ + row) * H_ + h];
        mmax = fmaxf(mmax, m[s]);
    }
    float Lt = 0.f, acc = 0.f;
#pragma unroll
    for (int s = 0; s < NSPLIT; ++s) {
        const float wgt = __expf(m[s] - mmax);
        Lt  += wgt * Ll[((size_t)s * ML_ + row) * H_ + h];
        acc += wgt * __bfloat162float(Op[((size_t)s * ML_ + row) * D_ + d]);
    }
    o_b[idx] = __float2bfloat16(acc / Lt);
}

// ---------------------------------------------------------------------------
// LayerNorm over D=256, one block per row.
// ---------------------------------------------------------------------------
__device__ __forceinline__ float ln_stat(float x, float* rs, float* rq,
                                         int tid, float* mean_out, float* rstd_out) {
    float s = x, q = x * x;
#pragma unroll
    for (int off = 32; off; off >>= 1) {
        s += __shfl_down(s, off);
        q += __shfl_down(q, off);
    }
    const int wid = tid >> 6, lane = tid & 63;
    if (lane == 0) { rs[wid] = s; rq[wid] = q; }
    __syncthreads();
    const float S = rs[0] + rs[1] + rs[2] + rs[3];
    const float Q = rq[0] + rq[1] + rq[2] + rq[3];
    const float mean = S * (1.f / D_);
    const float var = Q * (1.f / D_) - mean * mean;
    *mean_out = mean;
    *rstd_out = rsqrtf(var + 1e-5f);
    return x;
}

__global__ __launch_bounds__(256) void ln_to_bf16(const float* __restrict__ X,
                                                  const float* __restrict__ g,
                                                  const float* __restrict__ bb,
                                                  __hip_bfloat16* __restrict__ Y) {
    const int row = blockIdx.x, tid = threadIdx.x;
    __shared__ float rs[4], rq[4];
    float mean, rstd;
    const float x = ln_stat(X[(size_t)row * D_ + tid], rs, rq, tid, &mean, &rstd);
    Y[(size_t)row * D_ + tid] = __float2bfloat16((x - mean) * rstd * g[tid] + bb[tid]);
}

__global__ __launch_bounds__(256) void ln_residual(const float* __restrict__ X,
                                                   const float* __restrict__ g,
                                                   const float* __restrict__ bb,
                                                   const float* __restrict__ addx,
                                                   float* __restrict__ Y) {
    const int row = blockIdx.x, tid = threadIdx.x;
    __shared__ float rs[4], rq[4];
    float mean, rstd;
    const float x = ln_stat(X[(size_t)row * D_ + tid], rs, rq, tid, &mean, &rstd);
    Y[(size_t)row * D_ + tid] = (x - mean) * rstd * g[tid] + bb[tid] + addx[(size_t)row * D_ + tid];
}

// ---------------------------------------------------------------------------
extern "C" void kernel_launch(void* const* d_in, const int* in_sizes, int n_in,
                              void* d_out, int out_size, void* d_ws, size_t ws_size,
                              hipStream_t stream) {
    (void)in_sizes; (void)n_in; (void)out_size; (void)ws_size;
    const float* x   = (const float*)d_in[0];
    const float* src = (const float*)d_in[1];
    const float* F   = (const float*)d_in[2];
    const float* Wq  = (const float*)d_in[3];
    const float* Wk  = (const float*)d_in[4];
    const float* Wv  = (const float*)d_in[5];
    const float* Wm  = (const float*)d_in[6];
    const float* W1  = (const float*)d_in[7];
    const float* W2  = (const float*)d_in[8];
    const float* g1  = (const float*)d_in[9];
    const float* b1  = (const float*)d_in[10];
    const float* g2  = (const float*)d_in[11];
    const float* b2  = (const float*)d_in[12];
    float* out = (float*)d_out;

    // Workspace (24 MB):
    //   [0,2M)    x_b     [2M,4M)  src_b
    //   [4M,5.25M) weights bf16
    //   [6M,8M)   Qb   [8M,10M) Kb   [10M,12M) Vtb   [12M,14M) o_b
    //   [14M,22M) Opart bf16 (4 splits x 2MB)  -- dead after combine
    //   [22M,22.5M) Ml  [22.5M,23M) Ll          -- dead after combine
    //   [14M,18M) msg fp32 (after combine)   [18M,20M) m1_b   [20M,24M) h_b
    char* ws = (char*)d_ws;
    __hip_bfloat16* x_b   = (__hip_bfloat16*)(ws);
    __hip_bfloat16* src_b = (__hip_bfloat16*)(ws + (2u << 20));
    __hip_bfloat16* Wq_b  = (__hip_bfloat16*)(ws + (4u << 20));
    __hip_bfloat16* Wk_b  = (__hip_bfloat16*)(ws + (4u << 20) + 131072);
    __hip_bfloat16* Wv_b  = (__hip_bfloat16*)(ws + (4u << 20) + 2 * 131072);
    __hip_bfloat16* Wm_b  = (__hip_bfloat16*)(ws + (4u << 20) + 3 * 131072);
    __hip_bfloat16* W1_b  = (__hip_bfloat16*)(ws + (4u << 20) + 4 * 131072);
    __hip_bfloat16* W2_b  = (__hip_bfloat16*)(ws + (4u << 20) + 4 * 131072 + 524288);
    __hip_bfloat16* Qb   = (__hip_bfloat16*)(ws + (6u << 20));
    __hip_bfloat16* Kb   = (__hip_bfloat16*)(ws + (8u << 20));
    __hip_bfloat16* Vtb  = (__hip_bfloat16*)(ws + (10u << 20));
    __hip_bfloat16* o_b  = (__hip_bfloat16*)(ws + (12u << 20));
    __hip_bfloat16* Opart = (__hip_bfloat16*)(ws + (14u << 20));
    float* Ml  = (float*)(ws + (22u << 20));
    float* Ll  = (float*)(ws + (22u << 20) + 524288);
    float* msg = (float*)(ws + (14u << 20));
    __hip_bfloat16* m1_b = (__hip_bfloat16*)(ws + (18u << 20));
    __hip_bfloat16* h_b  = (__hip_bfloat16*)(ws + (20u << 20));

    dim3 blk(256);
    convert_all<<<dim3(2688), blk, 0, stream>>>(x, src, Wq, Wk, Wv, Wm, W1, W2,
                                                x_b, src_b, Wq_b, Wk_b, Wv_b, Wm_b, W1_b, W2_b);
    // Fused Q/K/Vt projections (one launch, 1024 blocks)
    proj_fused<<<dim3(1024), blk, 0, stream>>>(x_b, src_b, Wq_b, Wk_b, Wv_b, Qb, Kb, Vtb);
    // Attention: split-S partials + combine
    attn_mfma<<<dim3(L_ / 64, H_, B_ * NSPLIT), blk, 0, stream>>>(Qb, Kb, Vtb, F, Opart, Ml, Ll);
    attn_combine<<<dim3(ML_ * D_ / 256), blk, 0, stream>>>(Opart, Ml, Ll, o_b);
    // Out-proj + LN1
    gemm_bf16<false, float><<<dim3(ML_ / 64, D_ / 64), blk, 0, stream>>>(o_b, nullptr, Wm_b, msg, D_, D_, D_);
    ln_to_bf16<<<dim3(ML_), blk, 0, stream>>>(msg, g1, b1, m1_b);
    // MLP: W1 reads A split x_b/m1_b (fused concat), both lda=256
    gemm_bf16<true,  __hip_bfloat16><<<dim3(ML_ / 64, 512 / 64), blk, 0, stream>>>(x_b, m1_b, W1_b, h_b, 512, 512, 256);
    gemm_bf16<false, float><<<dim3(ML_ / 64, D_ / 64), blk, 0, stream>>>(h_b, nullptr, W2_b, msg, D_, 512, 512);
    // LN2 + residual
    ln_residual<<<dim3(ML_), blk, 0, stream>>>(msg, g2, b2, x, out);
}

// Round 6
// 211.380 us; speedup vs baseline: 2.8265x; 1.1251x over previous
//
#include <hip/hip_runtime.h>
#include <hip/hip_bf16.h>
#include <math.h>

// Problem constants
#define B_  2
#define L_  2048
#define S_  2048
#define D_  256
#define H_  8
#define HD_ 32
#define ML_ (B_ * L_)
#define MS_ (B_ * S_)
#define NSPLIT 4
#define SCHUNK (S_ / NSPLIT)   // 512

typedef __attribute__((ext_vector_type(8))) short short8;   // 8 bf16 (A/B frag)
typedef __attribute__((ext_vector_type(4))) float f32x4;    // C/D frag

// ---------------------------------------------------------------------------
// One-shot fp32 -> bf16 conversion of all GEMM operands.
// ---------------------------------------------------------------------------
__global__ __launch_bounds__(256) void convert_all(
    const float* __restrict__ x,  const float* __restrict__ src,
    const float* __restrict__ Wq, const float* __restrict__ Wk,
    const float* __restrict__ Wv, const float* __restrict__ Wm,
    const float* __restrict__ W1, const float* __restrict__ W2,
    __hip_bfloat16* xb,  __hip_bfloat16* srcb,
    __hip_bfloat16* Wqb, __hip_bfloat16* Wkb,
    __hip_bfloat16* Wvb, __hip_bfloat16* Wmb,
    __hip_bfloat16* W1b, __hip_bfloat16* W2b) {
    const size_t i4 = ((size_t)blockIdx.x * 256 + threadIdx.x) * 4;
    const float* sp; __hip_bfloat16* dp; size_t off;
    if      (i4 < 1048576) { sp = x;   dp = xb;   off = i4; }
    else if (i4 < 2097152) { sp = src; dp = srcb; off = i4 - 1048576; }
    else if (i4 < 2162688) { sp = Wq;  dp = Wqb;  off = i4 - 2097152; }
    else if (i4 < 2228224) { sp = Wk;  dp = Wkb;  off = i4 - 2162688; }
    else if (i4 < 2293760) { sp = Wv;  dp = Wvb;  off = i4 - 2228224; }
    else if (i4 < 2359296) { sp = Wm;  dp = Wmb;  off = i4 - 2293760; }
    else if (i4 < 2621440) { sp = W1;  dp = W1b;  off = i4 - 2359296; }
    else                   { sp = W2;  dp = W2b;  off = i4 - 2621440; }
    float4 v = *(const float4*)(sp + off);
    __hip_bfloat16 o0 = __float2bfloat16(v.x), o1 = __float2bfloat16(v.y);
    __hip_bfloat16 o2 = __float2bfloat16(v.z), o3 = __float2bfloat16(v.w);
    __hip_bfloat16* d = dp + off;
    d[0] = o0; d[1] = o1; d[2] = o2; d[3] = o3;
}

// ---------------------------------------------------------------------------
// Shared bf16 MFMA GEMM body: C tile [m0:m0+64, n0:n0+64] of A[.,K]@Bm[N,K]^T.
// Register prefetch of next k-tile across the barrier (lite double-buffer).
// A2: second A source for k>=256 (fused concat); lda = row stride of A/A2.
// ---------------------------------------------------------------------------
template <bool RELU, typename OutT>
__device__ __forceinline__ void gemm_body(const __hip_bfloat16* __restrict__ A,
                                          const __hip_bfloat16* __restrict__ A2,
                                          const __hip_bfloat16* __restrict__ Bm,
                                          OutT* __restrict__ C,
                                          int N, int K, int lda, int m0, int n0,
                                          __hip_bfloat16 (&As)[64][72],
                                          __hip_bfloat16 (&Bs)[64][72]) {
    const int tid  = threadIdx.x;
    const int w    = tid >> 6;
    const int lane = tid & 63;
    const int colL = lane & 15;
    const int quad = lane >> 4;
    const int mh = (w & 1) * 32, nh = (w >> 1) * 32;
    const int srow = tid >> 3;          // 0..31, two passes -> 64 rows
    const int scg  = (tid & 7) * 8;     // col group (8 bf16 = 16 B)

    f32x4 acc[2][2] = {};

    auto loadA = [&](int p, int k0) -> short8 {
        const __hip_bfloat16* Asrc = A; int kk = k0;
        if (A2 && k0 >= 256) { Asrc = A2; kk = k0 - 256; }
        return *(const short8*)(Asrc + (size_t)(m0 + srow + p * 32) * lda + kk + scg);
    };
    auto loadB = [&](int p, int k0) -> short8 {
        return *(const short8*)(Bm + (size_t)(n0 + srow + p * 32) * K + k0 + scg);
    };

    short8 ra[2], rb[2];
#pragma unroll
    for (int p = 0; p < 2; ++p) { ra[p] = loadA(p, 0); rb[p] = loadB(p, 0); }

    for (int k0 = 0; k0 < K; k0 += 64) {
        __syncthreads();
#pragma unroll
        for (int p = 0; p < 2; ++p) {
            *(short8*)&As[srow + p * 32][scg] = ra[p];
            *(short8*)&Bs[srow + p * 32][scg] = rb[p];
        }
        __syncthreads();
        if (k0 + 64 < K) {
#pragma unroll
            for (int p = 0; p < 2; ++p) { ra[p] = loadA(p, k0 + 64); rb[p] = loadB(p, k0 + 64); }
        }
#pragma unroll
        for (int ks = 0; ks < 2; ++ks) {
            short8 af[2], bf[2];
#pragma unroll
            for (int i = 0; i < 2; ++i)
                af[i] = *(const short8*)&As[mh + i * 16 + colL][ks * 32 + quad * 8];
#pragma unroll
            for (int j = 0; j < 2; ++j)
                bf[j] = *(const short8*)&Bs[nh + j * 16 + colL][ks * 32 + quad * 8];
#pragma unroll
            for (int i = 0; i < 2; ++i)
#pragma unroll
                for (int j = 0; j < 2; ++j)
                    acc[i][j] = __builtin_amdgcn_mfma_f32_16x16x32_bf16(af[i], bf[j], acc[i][j], 0, 0, 0);
        }
    }
#pragma unroll
    for (int i = 0; i < 2; ++i)
#pragma unroll
        for (int r = 0; r < 4; ++r) {
            const size_t row = m0 + mh + i * 16 + quad * 4 + r;
#pragma unroll
            for (int j = 0; j < 2; ++j) {
                float v = acc[i][j][r];
                if (RELU) v = fmaxf(v, 0.f);
                C[row * N + n0 + nh + j * 16 + colL] = (OutT)v;
            }
        }
}

template <bool RELU, typename OutT>
__global__ __launch_bounds__(256) void gemm_bf16(const __hip_bfloat16* __restrict__ A,
                                                 const __hip_bfloat16* __restrict__ A2,
                                                 const __hip_bfloat16* __restrict__ Bm,
                                                 OutT* __restrict__ C,
                                                 int N, int K, int lda) {
    __shared__ __hip_bfloat16 As[64][72];
    __shared__ __hip_bfloat16 Bs[64][72];
    gemm_body<RELU, OutT>(A, A2, Bm, C, N, K, lda,
                          blockIdx.x * 64, blockIdx.y * 64, As, Bs);
}

// ---------------------------------------------------------------------------
// Fused Q/K/Vt projection GEMMs in one launch (1024 blocks).
// ---------------------------------------------------------------------------
__global__ __launch_bounds__(256) void proj_fused(const __hip_bfloat16* __restrict__ x_b,
                                                  const __hip_bfloat16* __restrict__ src_b,
                                                  const __hip_bfloat16* __restrict__ Wq_b,
                                                  const __hip_bfloat16* __restrict__ Wk_b,
                                                  const __hip_bfloat16* __restrict__ Wv_b,
                                                  __hip_bfloat16* __restrict__ Qb,
                                                  __hip_bfloat16* __restrict__ Kb,
                                                  __hip_bfloat16* __restrict__ Vtb) {
    __shared__ __hip_bfloat16 As[64][72];
    __shared__ __hip_bfloat16 Bs[64][72];
    const int id = blockIdx.x;
    if (id < 256) {
        gemm_body<false, __hip_bfloat16>(x_b, nullptr, Wq_b, Qb, 256, 256, 256,
                                         (id >> 2) * 64, (id & 3) * 64, As, Bs);
    } else if (id < 512) {
        const int t = id - 256;
        gemm_body<false, __hip_bfloat16>(src_b, nullptr, Wk_b, Kb, 256, 256, 256,
                                         (t >> 2) * 64, (t & 3) * 64, As, Bs);
    } else {
        const int t = id - 512;
        const int b = t >> 7, u = t & 127;
        gemm_body<false, __hip_bfloat16>(Wv_b, nullptr, src_b + (size_t)b * S_ * D_,
                                         Vtb + (size_t)b * D_ * S_, S_, 256, 256,
                                         (u & 3) * 64, (u >> 2) * 64, As, Bs);
    }
}

// ---------------------------------------------------------------------------
// Flash attention, bf16 MFMA, split-S partials.
// __launch_bounds__(256,4): cap 128 VGPR -> NO spills; HW still co-resides
// 8 waves/SIMD at the compiler's natural ~56 VGPR. (256,8) forced 32 VGPR
// and scratch-spilled the inner loop (round-5 regression).
// Ml/Ll layout [split][h][row]: contiguous 64-row runs per block.
// ---------------------------------------------------------------------------
__global__ __launch_bounds__(256, 4) void attn_mfma(const __hip_bfloat16* __restrict__ Qb,
                                                    const __hip_bfloat16* __restrict__ Kb,
                                                    const __hip_bfloat16* __restrict__ Vtb,
                                                    const float* __restrict__ F,
                                                    __hip_bfloat16* __restrict__ Op,
                                                    float* __restrict__ Ml,
                                                    float* __restrict__ Ll) {
    const int tid  = threadIdx.x;
    const int w    = tid >> 6;
    const int lane = tid & 63;
    const int colL = lane & 15;
    const int quad = lane >> 4;

    const int b     = blockIdx.z >> 2;
    const int split = blockIdx.z & 3;
    const int h     = blockIdx.y;
    const int qw    = blockIdx.x * 64 + w * 16;

    __shared__ __hip_bfloat16 Pw[4][16][72];

    const short8 aq = *(const short8*)(Qb + ((size_t)(b * L_ + qw + colL)) * D_ + h * HD_ + quad * 8);

    float m_run[4] = {-INFINITY, -INFINITY, -INFINITY, -INFINITY};
    float l_run[4] = {0.f, 0.f, 0.f, 0.f};
    f32x4 o0 = {0.f, 0.f, 0.f, 0.f}, o1 = {0.f, 0.f, 0.f, 0.f};

    const float scale = 0.17677669529663687f;
    const __hip_bfloat16* kbase  = Kb  + ((size_t)(b * S_ + colL)) * D_ + h * HD_ + quad * 8;
    const __hip_bfloat16* vtbase = Vtb + ((size_t)b) * D_ * S_ + ((size_t)(h * HD_ + colL)) * S_ + quad * 8;
    const float* fbase = F + ((size_t)(b * L_ + qw + quad * 4)) * S_ + colL;

    const int send = split * SCHUNK + SCHUNK;
#pragma unroll 1
    for (int s0 = split * SCHUNK; s0 < send; s0 += 64) {
        f32x4 cc[4];
#pragma unroll
        for (int n = 0; n < 4; ++n) {
            short8 kf = *(const short8*)(kbase + (size_t)(s0 + n * 16) * D_);
            f32x4 z = {0.f, 0.f, 0.f, 0.f};
            cc[n] = __builtin_amdgcn_mfma_f32_16x16x32_bf16(aq, kf, z, 0, 0, 0);
        }
        float tmax[4] = {-INFINITY, -INFINITY, -INFINITY, -INFINITY};
#pragma unroll
        for (int n = 0; n < 4; ++n)
#pragma unroll
            for (int r = 0; r < 4; ++r) {
                float fv = fbase[(size_t)r * S_ + s0 + n * 16];
                float v = cc[n][r] * scale * fv;
                cc[n][r] = v;
                tmax[r] = fmaxf(tmax[r], v);
            }
#pragma unroll
        for (int r = 0; r < 4; ++r) {
            float t = tmax[r];
            t = fmaxf(t, __shfl_xor(t, 1));
            t = fmaxf(t, __shfl_xor(t, 2));
            t = fmaxf(t, __shfl_xor(t, 4));
            t = fmaxf(t, __shfl_xor(t, 8));
            tmax[r] = t;
        }
        float alpha[4];
#pragma unroll
        for (int r = 0; r < 4; ++r) {
            float mn = fmaxf(m_run[r], tmax[r]);
            alpha[r] = __expf(m_run[r] - mn);
            m_run[r] = mn;
            o0[r] *= alpha[r];
            o1[r] *= alpha[r];
        }
        float rsum[4] = {0.f, 0.f, 0.f, 0.f};
#pragma unroll
        for (int n = 0; n < 4; ++n)
#pragma unroll
            for (int r = 0; r < 4; ++r) {
                float p = __expf(cc[n][r] - m_run[r]);
                rsum[r] += p;
                Pw[w][quad * 4 + r][n * 16 + colL] = __float2bfloat16(p);
            }
#pragma unroll
        for (int r = 0; r < 4; ++r) {
            float t = rsum[r];
            t += __shfl_xor(t, 1);
            t += __shfl_xor(t, 2);
            t += __shfl_xor(t, 4);
            t += __shfl_xor(t, 8);
            l_run[r] = l_run[r] * alpha[r] + t;
        }
        short8 a0 = *(const short8*)(&Pw[w][colL][quad * 8]);
        short8 a1 = *(const short8*)(&Pw[w][colL][32 + quad * 8]);
#pragma unroll
        for (int ks = 0; ks < 2; ++ks) {
            short8 ap = ks ? a1 : a0;
#pragma unroll
            for (int nt = 0; nt < 2; ++nt) {
                short8 vf = *(const short8*)(vtbase + (size_t)nt * 16 * S_ + s0 + ks * 32);
                if (nt == 0) o0 = __builtin_amdgcn_mfma_f32_16x16x32_bf16(ap, vf, o0, 0, 0, 0);
                else         o1 = __builtin_amdgcn_mfma_f32_16x16x32_bf16(ap, vf, o1, 0, 0, 0);
            }
        }
    }

    // Partial epilogue: unnormalized O (bf16, 64B-sector aligned) + m,l.
#pragma unroll
    for (int r = 0; r < 4; ++r) {
        const size_t row = (size_t)(b * L_ + qw + quad * 4 + r);
        const size_t po = ((size_t)split * ML_ + row) * D_ + h * HD_;
        Op[po + colL]      = __float2bfloat16(o0[r]);
        Op[po + 16 + colL] = __float2bfloat16(o1[r]);
        if (colL == 0) {
            const size_t ml = ((size_t)split * H_ + h) * ML_ + row;
            Ml[ml] = m_run[r];
            Ll[ml] = l_run[r];
        }
    }
}

// ---------------------------------------------------------------------------
// Combine NSPLIT partials -> normalized o_b (bf16).
// ---------------------------------------------------------------------------
__global__ __launch_bounds__(256) void attn_combine(const __hip_bfloat16* __restrict__ Op,
                                                    const float* __restrict__ Ml,
                                                    const float* __restrict__ Ll,
                                                    __hip_bfloat16* __restrict__ o_b) {
    const int idx = blockIdx.x * 256 + threadIdx.x;   // over ML_*D_
    const int row = idx >> 8, d = idx & 255, h = d >> 5;
    float m[NSPLIT];
    float mmax = -INFINITY;
#pragma unroll
    for (int s = 0; s < NSPLIT; ++s) {
        m[s] = Ml[((size_t)s * H_ + h) * ML_ + row];
        mmax = fmaxf(mmax, m[s]);
    }
    float Lt = 0.f, acc = 0.f;
#pragma unroll
    for (int s = 0; s < NSPLIT; ++s) {
        const float wgt = __expf(m[s] - mmax);
        Lt  += wgt * Ll[((size_t)s * H_ + h) * ML_ + row];
        acc += wgt * __bfloat162float(Op[((size_t)s * ML_ + row) * D_ + d]);
    }
    o_b[idx] = __float2bfloat16(acc / Lt);
}

// ---------------------------------------------------------------------------
// LayerNorm over D=256, one block per row.
// ---------------------------------------------------------------------------
__device__ __forceinline__ float ln_stat(float x, float* rs, float* rq,
                                         int tid, float* mean_out, float* rstd_out) {
    float s = x, q = x * x;
#pragma unroll
    for (int off = 32; off; off >>= 1) {
        s += __shfl_down(s, off);
        q += __shfl_down(q, off);
    }
    const int wid = tid >> 6, lane = tid & 63;
    if (lane == 0) { rs[wid] = s; rq[wid] = q; }
    __syncthreads();
    const float S = rs[0] + rs[1] + rs[2] + rs[3];
    const float Q = rq[0] + rq[1] + rq[2] + rq[3];
    const float mean = S * (1.f / D_);
    const float var = Q * (1.f / D_) - mean * mean;
    *mean_out = mean;
    *rstd_out = rsqrtf(var + 1e-5f);
    return x;
}

__global__ __launch_bounds__(256) void ln_to_bf16(const float* __restrict__ X,
                                                  const float* __restrict__ g,
                                                  const float* __restrict__ bb,
                                                  __hip_bfloat16* __restrict__ Y) {
    const int row = blockIdx.x, tid = threadIdx.x;
    __shared__ float rs[4], rq[4];
    float mean, rstd;
    const float x = ln_stat(X[(size_t)row * D_ + tid], rs, rq, tid, &mean, &rstd);
    Y[(size_t)row * D_ + tid] = __float2bfloat16((x - mean) * rstd * g[tid] + bb[tid]);
}

__global__ __launch_bounds__(256) void ln_residual(const float* __restrict__ X,
                                                   const float* __restrict__ g,
                                                   const float* __restrict__ bb,
                                                   const float* __restrict__ addx,
                                                   float* __restrict__ Y) {
    const int row = blockIdx.x, tid = threadIdx.x;
    __shared__ float rs[4], rq[4];
    float mean, rstd;
    const float x = ln_stat(X[(size_t)row * D_ + tid], rs, rq, tid, &mean, &rstd);
    Y[(size_t)row * D_ + tid] = (x - mean) * rstd * g[tid] + bb[tid] + addx[(size_t)row * D_ + tid];
}

// ---------------------------------------------------------------------------
extern "C" void kernel_launch(void* const* d_in, const int* in_sizes, int n_in,
                              void* d_out, int out_size, void* d_ws, size_t ws_size,
                              hipStream_t stream) {
    (void)in_sizes; (void)n_in; (void)out_size; (void)ws_size;
    const float* x   = (const float*)d_in[0];
    const float* src = (const float*)d_in[1];
    const float* F   = (const float*)d_in[2];
    const float* Wq  = (const float*)d_in[3];
    const float* Wk  = (const float*)d_in[4];
    const float* Wv  = (const float*)d_in[5];
    const float* Wm  = (const float*)d_in[6];
    const float* W1  = (const float*)d_in[7];
    const float* W2  = (const float*)d_in[8];
    const float* g1  = (const float*)d_in[9];
    const float* b1  = (const float*)d_in[10];
    const float* g2  = (const float*)d_in[11];
    const float* b2  = (const float*)d_in[12];
    float* out = (float*)d_out;

    // Workspace (24 MB):
    //   [0,2M)    x_b     [2M,4M)  src_b
    //   [4M,5.25M) weights bf16
    //   [6M,8M)   Qb   [8M,10M) Kb   [10M,12M) Vtb   [12M,14M) o_b
    //   [14M,22M) Opart bf16 (4 splits x 2MB)  -- dead after combine
    //   [22M,22.5M) Ml  [22.5M,23M) Ll          -- dead after combine
    //   [14M,18M) msg fp32 (after combine)   [18M,20M) m1_b   [20M,24M) h_b
    char* ws = (char*)d_ws;
    __hip_bfloat16* x_b   = (__hip_bfloat16*)(ws);
    __hip_bfloat16* src_b = (__hip_bfloat16*)(ws + (2u << 20));
    __hip_bfloat16* Wq_b  = (__hip_bfloat16*)(ws + (4u << 20));
    __hip_bfloat16* Wk_b  = (__hip_bfloat16*)(ws + (4u << 20) + 131072);
    __hip_bfloat16* Wv_b  = (__hip_bfloat16*)(ws + (4u << 20) + 2 * 131072);
    __hip_bfloat16* Wm_b  = (__hip_bfloat16*)(ws + (4u << 20) + 3 * 131072);
    __hip_bfloat16* W1_b  = (__hip_bfloat16*)(ws + (4u << 20) + 4 * 131072);
    __hip_bfloat16* W2_b  = (__hip_bfloat16*)(ws + (4u << 20) + 4 * 131072 + 524288);
    __hip_bfloat16* Qb   = (__hip_bfloat16*)(ws + (6u << 20));
    __hip_bfloat16* Kb   = (__hip_bfloat16*)(ws + (8u << 20));
    __hip_bfloat16* Vtb  = (__hip_bfloat16*)(ws + (10u << 20));
    __hip_bfloat16* o_b  = (__hip_bfloat16*)(ws + (12u << 20));
    __hip_bfloat16* Opart = (__hip_bfloat16*)(ws + (14u << 20));
    float* Ml  = (float*)(ws + (22u << 20));
    float* Ll  = (float*)(ws + (22u << 20) + 524288);
    float* msg = (float*)(ws + (14u << 20));
    __hip_bfloat16* m1_b = (__hip_bfloat16*)(ws + (18u << 20));
    __hip_bfloat16* h_b  = (__hip_bfloat16*)(ws + (20u << 20));

    dim3 blk(256);
    convert_all<<<dim3(2688), blk, 0, stream>>>(x, src, Wq, Wk, Wv, Wm, W1, W2,
                                                x_b, src_b, Wq_b, Wk_b, Wv_b, Wm_b, W1_b, W2_b);
    // Fused Q/K/Vt projections
    proj_fused<<<dim3(1024), blk, 0, stream>>>(x_b, src_b, Wq_b, Wk_b, Wv_b, Qb, Kb, Vtb);
    // Attention: split-S partials + combine
    attn_mfma<<<dim3(L_ / 64, H_, B_ * NSPLIT), blk, 0, stream>>>(Qb, Kb, Vtb, F, Opart, Ml, Ll);
    attn_combine<<<dim3(ML_ * D_ / 256), blk, 0, stream>>>(Opart, Ml, Ll, o_b);
    // Out-proj + LN1
    gemm_bf16<false, float><<<dim3(ML_ / 64, D_ / 64), blk, 0, stream>>>(o_b, nullptr, Wm_b, msg, D_, D_, D_);
    ln_to_bf16<<<dim3(ML_), blk, 0, stream>>>(msg, g1, b1, m1_b);
    // MLP: W1 reads A split x_b/m1_b (fused concat), both lda=256
    gemm_bf16<true,  __hip_bfloat16><<<dim3(ML_ / 64, 512 / 64), blk, 0, stream>>>(x_b, m1_b, W1_b, h_b, 512, 512, 256);
    gemm_bf16<false, float><<<dim3(ML_ / 64, D_ / 64), blk, 0, stream>>>(h_b, nullptr, W2_b, msg, D_, 512, 512);
    // LN2 + residual
    ln_residual<<<dim3(ML_), blk, 0, stream>>>(msg, g2, b2, x, out);
}